// Round 7
// baseline (330.864 us; speedup 1.0000x reference)
//
#include <hip/hip_runtime.h>

// MFB fused non-local block, round 7.
// - av GEMM restructured: wg = 64m x 256c, splitK=1, grid 256. Pt read once
//   (no c-duplication), Kb L2-resident, epilogue stores avTb bf16 directly
//   (LDS transpose) -> avPart + avred + 1 launch eliminated.
// - prep_k merges castw3 + wf + rowsum zeroing: 10 -> 7 dispatches.

#define N_ 4096
#define C_ 512
#define IC_ 256
#define B_ 4

typedef __bf16 bf16_t;
typedef __bf16 bf16x8 __attribute__((ext_vector_type(8)));
typedef __bf16 bf16x4 __attribute__((ext_vector_type(4)));
typedef float f32x4 __attribute__((ext_vector_type(4)));

#define GLD(g, l) __builtin_amdgcn_global_load_lds(                              \
    (const __attribute__((address_space(1))) void*)(g),                          \
    (__attribute__((address_space(3))) void*)(l), 16, 0, 0)

// ---------------------------------------------------------------------------
// C[128x128] += A[m0.., K] * Bt[n0.., K]^T, bf16 in, fp32 acc. K mult of 64.
// 256 threads = 4 waves; wave (wr,wc) owns 64x64; acc[4][4] of f32x4.
// C/D layout (m89/m91): (i,j,reg) -> row wr+i*16+q*4+reg, col wc+j*16+l15.
// LDS: XOR-swizzled 64-elem rows; slot (row, c) holds global chunk c^(row&7).
// ---------------------------------------------------------------------------
__device__ __forceinline__ void gemm_bt_128x128(
    const bf16_t* __restrict__ A, int lda,
    const bf16_t* __restrict__ Bt, int ldb,
    int K, int kt0, int m0, int n0,
    bf16_t* lsA, bf16_t* lsB, f32x4 acc[4][4])
{
    const int tid  = threadIdx.x;
    const int wave = tid >> 6, lane = tid & 63;
    const int wr = (wave >> 1) * 64, wc = (wave & 1) * 64;
    const int q = lane >> 4, l15 = lane & 15;
    const int srow = lane >> 3;                         // 0..7
    const int scol = (((lane & 7) ^ (srow & 7)) * 8);   // swizzled 8-elem chunk
    const int swz  = l15 & 7;

    for (int kt = kt0; kt < kt0 + K; kt += 64) {
#pragma unroll
        for (int c = 0; c < 4; ++c) {
            const int ch = wave * 4 + c;
            GLD(A  + (size_t)(m0 + ch * 8 + srow) * lda + kt + scol, lsA + ch * 512);
            GLD(Bt + (size_t)(n0 + ch * 8 + srow) * ldb + kt + scol, lsB + ch * 512);
        }
        __syncthreads();
#pragma unroll
        for (int ks = 0; ks < 2; ++ks) {
            bf16x8 af[4], bfr[4];
            const int co = ((ks * 4 + q) ^ swz) * 8;
#pragma unroll
            for (int i = 0; i < 4; ++i) {
                af[i]  = *(const bf16x8*)&lsA[(wr + i * 16 + l15) * 64 + co];
                bfr[i] = *(const bf16x8*)&lsB[(wc + i * 16 + l15) * 64 + co];
            }
#pragma unroll
            for (int i = 0; i < 4; ++i)
#pragma unroll
                for (int j = 0; j < 4; ++j)
                    acc[i][j] = __builtin_amdgcn_mfma_f32_16x16x32_bf16(
                        af[i], bfr[j], acc[i][j], 0, 0, 0);
        }
        __syncthreads();
    }
}

#define ACC_ZERO(acc)                                                           \
    _Pragma("unroll") for (int i = 0; i < 4; ++i)                               \
    _Pragma("unroll") for (int j = 0; j < 4; ++j)                               \
        acc[i][j] = f32x4{0.f, 0.f, 0.f, 0.f};

// ---- prep: castw3 (blocks 0..1535) | wf compose (1536..2047) | zero rowsum
__global__ __launch_bounds__(256) void prep_k(
    const float* __restrict__ wk, const float* __restrict__ wv,
    const float* __restrict__ wq,
    const float* __restrict__ wwg, const float* __restrict__ wout,
    const float* __restrict__ bout,
    const float* __restrict__ g1, const float* __restrict__ b1,
    const float* __restrict__ m1, const float* __restrict__ v1,
    const float* __restrict__ g2, const float* __restrict__ b2,
    const float* __restrict__ m2, const float* __restrict__ v2,
    bf16_t* __restrict__ Wb3, bf16_t* __restrict__ Wfb,
    float* __restrict__ bfv, float* __restrict__ rowsum)
{
    const int bid = blockIdx.x;
    __shared__ float ws[256];
    __shared__ float red[4];

    if (bid < 1536) {                 // cast wk|wv|wq to bf16
        const int i = bid * 256 + threadIdx.x;
        float v;
        if      (i < 131072) v = wk[i];
        else if (i < 262144) v = wv[i - 131072];
        else                 v = wq[i - 262144];
        Wb3[i] = (bf16_t)v;
    } else if (bid < 2048) {          // Wf = diag(s2) wout diag(s1) wwg + bias
        const int o = bid - 1536;     // 0..511
        const int j = threadIdx.x;    // 0..255
        const float s1 = g1[j] * rsqrtf(v1[j] + 1e-5f);
        const float wo = wout[o * 256 + j];
        ws[j] = wo * s1;
        float bp = wo * (b1[j] - m1[j] * s1);
#pragma unroll
        for (int off = 32; off > 0; off >>= 1) bp += __shfl_down(bp, off);
        if ((j & 63) == 0) red[j >> 6] = bp;
        __syncthreads();

        float acc = 0.f;
#pragma unroll 4
        for (int ic = 0; ic < 256; ++ic)
            acc += ws[ic] * wwg[ic * 256 + j];

        const float s2 = g2[o] * rsqrtf(v2[o] + 1e-5f);
        Wfb[o * 256 + j] = (bf16_t)(acc * s2);
        if (j == 0)
            bfv[o] = s2 * (red[0] + red[1] + red[2] + red[3] + bout[o])
                     - s2 * m2[o] + b2[o];
    } else {                          // zero rowsum[b][n] (16384 floats)
        rowsum[(bid - 2048) * 256 + threadIdx.x] = 0.f;
    }
}

// --------------------------------------------- xA [b,c,n] -> xAt [b,n,c] bf16
__global__ __launch_bounds__(256) void txa_k(
    const float* __restrict__ xA, bf16_t* __restrict__ xAt)
{
    __shared__ float t[32][33];
    const int b = blockIdx.z;
    const int n0 = blockIdx.x * 32, c0 = blockIdx.y * 32;
    const int tx = threadIdx.x, ty = threadIdx.y;
    const float* X = xA + (size_t)b * C_ * N_;
    bf16_t* Y = xAt + (size_t)b * N_ * C_;
#pragma unroll
    for (int r = 0; r < 4; ++r)
        t[ty + r * 8][tx] = X[(size_t)(c0 + ty + r * 8) * N_ + n0 + tx];
    __syncthreads();
#pragma unroll
    for (int r = 0; r < 4; ++r)
        Y[(size_t)(n0 + ty + r * 8) * C_ + c0 + tx] = (bf16_t)t[tx][ty + r * 8];
}

// ------------------------------------------ conv KVQ: W[o,c] * xAt[n,c]^T
__global__ __launch_bounds__(256) void conv_mfma_k(
    const bf16_t* __restrict__ Wb3,
    const float* __restrict__ bk, const float* __restrict__ bv,
    const float* __restrict__ bq, const bf16_t* __restrict__ xAt,
    bf16_t* __restrict__ Kb, bf16_t* __restrict__ Vt, bf16_t* __restrict__ Qt)
{
    __shared__ bf16_t smem[16384];
    const int which = blockIdx.z % 3, b = blockIdx.z / 3;
    const bf16_t* A = Wb3 + which * 131072;
    const float* bias = (which == 0) ? bk : (which == 1 ? bv : bq);
    const bf16_t* Bt = xAt + (size_t)b * N_ * C_;
    const int n0 = blockIdx.x * 128, m0 = blockIdx.y * 128;

    f32x4 acc[4][4];
    ACC_ZERO(acc);
    gemm_bt_128x128(A, C_, Bt, C_, C_, 0, m0, n0, smem, smem + 8192, acc);

    const int lane = threadIdx.x & 63, wave = threadIdx.x >> 6;
    const int q = lane >> 4, l15 = lane & 15;
    const int wr = (wave >> 1) * 64, wc = (wave & 1) * 64;

    if (which == 0) {                     // K: [c, n], n contiguous
        bf16_t* Y = Kb + (size_t)b * IC_ * N_;
#pragma unroll
        for (int i = 0; i < 4; ++i)
#pragma unroll
            for (int r = 0; r < 4; ++r) {
                const int o = m0 + wr + i * 16 + q * 4 + r;
                const float bo = bias[o];
#pragma unroll
                for (int j = 0; j < 4; ++j)
                    Y[(size_t)o * N_ + n0 + wc + j * 16 + l15] =
                        (bf16_t)(acc[i][j][r] + bo);
            }
    } else {                              // V/Q: [n, c], c contiguous
        bf16_t* Y = ((which == 1) ? Vt : Qt) + (size_t)b * N_ * IC_;
#pragma unroll
        for (int i = 0; i < 4; ++i) {
            const int ob = m0 + wr + i * 16 + q * 4;
            float bo[4];
#pragma unroll
            for (int r = 0; r < 4; ++r) bo[r] = bias[ob + r];
#pragma unroll
            for (int j = 0; j < 4; ++j) {
                const int n = n0 + wc + j * 16 + l15;
                bf16x4 v4;
#pragma unroll
                for (int r = 0; r < 4; ++r) v4[r] = (bf16_t)(acc[i][j][r] + bo[r]);
                *(bf16x4*)&Y[(size_t)n * IC_ + ob] = v4;
            }
        }
    }
}

// ---- S^T GEMM (batched): D[m,n]=Qt[m,:].Vt[n,:]; write Pt[b][m,n]=exp bf16,
//      rowsum[b][n] += column sums. LDS stage (stride 136) -> b128 stores.
__global__ __launch_bounds__(256) void s_mfma_t_k(
    const bf16_t* __restrict__ Qt, const bf16_t* __restrict__ Vt,
    bf16_t* __restrict__ Pt, float* __restrict__ rowsum)
{
    __shared__ bf16_t smem[17408];
    const int b  = blockIdx.z;
    const int n0 = blockIdx.x * 128;      // cols (n)
    const int m0 = blockIdx.y * 128;      // rows (m)
    const size_t NIC = (size_t)N_ * IC_;
    const bf16_t* Qb = Qt + (size_t)b * NIC;
    const bf16_t* Vb = Vt + (size_t)b * NIC;
    bf16_t* Pb = Pt + (size_t)b * N_ * N_;
    float* rs = rowsum + b * N_;

    f32x4 acc[4][4];
    ACC_ZERO(acc);
    gemm_bt_128x128(Qb, IC_, Vb, IC_, IC_, 0, m0, n0, smem, smem + 8192, acc);

    const int tid = threadIdx.x;
    const int lane = tid & 63, wave = tid >> 6;
    const int q = lane >> 4, l15 = lane & 15;
    const int wr = (wave >> 1) * 64, wc = (wave & 1) * 64;

#pragma unroll
    for (int j = 0; j < 4; ++j) {
        float cs = 0.f;
#pragma unroll
        for (int i = 0; i < 4; ++i)
#pragma unroll
            for (int r = 0; r < 4; ++r) {
                const float e = __expf(acc[i][j][r]);
                cs += e;
                smem[(wr + i * 16 + q * 4 + r) * 136 + wc + j * 16 + l15] = (bf16_t)e;
            }
        cs += __shfl_xor(cs, 16);
        cs += __shfl_xor(cs, 32);
        if (q == 0) atomicAdd(&rs[n0 + wc + j * 16 + l15], cs);
    }
    __syncthreads();

    const int rr = tid >> 4;              // 0..15
    const int cc = (tid & 15) * 8;        // 0..120
#pragma unroll
    for (int p = 0; p < 8; ++p) {
        const int mm = rr + p * 16;
        const bf16x8 v = *(const bf16x8*)&smem[mm * 136 + cc];
        *(bf16x8*)&Pb[(size_t)(m0 + mm) * N_ + n0 + cc] = v;
    }
}

// --------------- K'[b][c,n] = K[b][c,n] / rowsum[b][n], in-place (batched)
__global__ __launch_bounds__(256) void kscale_k(
    bf16_t* __restrict__ Kb, const float* __restrict__ rowsum)
{
    const size_t i8 = ((size_t)blockIdx.x * 256 + threadIdx.x) * 8;  // 2048 blocks
    const int n = (int)(i8 & (N_ - 1));
    const int b = (int)(i8 >> 20);                 // IC_*N_ = 2^20
    const float* rs = rowsum + b * N_;
    bf16x8 v = *(bf16x8*)&Kb[i8];
    const f32x4 r0 = *(const f32x4*)&rs[n];
    const f32x4 r1 = *(const f32x4*)&rs[n + 4];
#pragma unroll
    for (int k = 0; k < 4; ++k) {
        v[k]     = (bf16_t)((float)v[k]     / r0[k]);
        v[4 + k] = (bf16_t)((float)v[4 + k] / r1[k]);
    }
    *(bf16x8*)&Kb[i8] = v;
}

// ---- av GEMM: wg = 64m x 256c, splitK=1. avTb[b][m][c] = Pt[b][m,:].K'[b][c,:]^T
//      A-rows shared by all 4 waves; wave w owns c-slice [w*64, w*64+64).
__global__ __launch_bounds__(256) void av_mfma_k(
    const bf16_t* __restrict__ Pt, const bf16_t* __restrict__ Kb,
    bf16_t* __restrict__ avTb)
{
    __shared__ bf16_t smem[20480];        // lsA 64x64 (8KB) | lsB 256x64 (32KB)
    bf16_t* lsA = smem;
    bf16_t* lsB = smem + 4096;
    const int b  = blockIdx.y;
    const int m0 = blockIdx.x * 64;
    const size_t NIC = (size_t)N_ * IC_;
    const bf16_t* Pb  = Pt + (size_t)b * N_ * N_ + (size_t)m0 * N_;
    const bf16_t* Kbb = Kb + (size_t)b * NIC;

    const int tid = threadIdx.x;
    const int wave = tid >> 6, lane = tid & 63;
    const int q = lane >> 4, l15 = lane & 15;
    const int srow = lane >> 3;
    const int scol = (((lane & 7) ^ (srow & 7)) * 8);
    const int swz  = l15 & 7;

    f32x4 acc[4][4];
    ACC_ZERO(acc);

    for (int kt = 0; kt < N_; kt += 64) {
#pragma unroll
        for (int c = 0; c < 2; ++c) {     // A: 8 chunks of 8 m-rows
            const int ch = wave * 2 + c;
            GLD(Pb + (size_t)(ch * 8 + srow) * N_ + kt + scol, lsA + ch * 512);
        }
#pragma unroll
        for (int c = 0; c < 8; ++c) {     // B: 32 chunks of 8 c-rows
            const int ch = wave * 8 + c;
            GLD(Kbb + (size_t)(ch * 8 + srow) * N_ + kt + scol, lsB + ch * 512);
        }
        __syncthreads();
#pragma unroll
        for (int ks = 0; ks < 2; ++ks) {
            const int co = ((ks * 4 + q) ^ swz) * 8;
            bf16x8 af[4], bfr[4];
#pragma unroll
            for (int i = 0; i < 4; ++i) {
                af[i]  = *(const bf16x8*)&lsA[(i * 16 + l15) * 64 + co];
                bfr[i] = *(const bf16x8*)&lsB[(wave * 64 + i * 16 + l15) * 64 + co];
            }
#pragma unroll
            for (int i = 0; i < 4; ++i)
#pragma unroll
                for (int j = 0; j < 4; ++j)
                    acc[i][j] = __builtin_amdgcn_mfma_f32_16x16x32_bf16(
                        af[i], bfr[j], acc[i][j], 0, 0, 0);
        }
        __syncthreads();
    }

    // epilogue: stage 64 x 256 bf16 (stride 264, 16B-aligned rows) -> b128 rows
#pragma unroll
    for (int i = 0; i < 4; ++i)
#pragma unroll
        for (int j = 0; j < 4; ++j)
#pragma unroll
            for (int r = 0; r < 4; ++r)
                smem[(i * 16 + q * 4 + r) * 264 + wave * 64 + j * 16 + l15] =
                    (bf16_t)acc[i][j][r];
    __syncthreads();

    bf16_t* Y = avTb + (size_t)b * NIC + (size_t)m0 * IC_;
    const int erow = tid >> 2;            // 0..63
    const int ecol = (tid & 3) * 8;       // 0,8,16,24
#pragma unroll
    for (int p = 0; p < 8; ++p) {
        const int col = ecol + p * 32;
        const bf16x8 v = *(const bf16x8*)&smem[erow * 264 + col];
        *(bf16x8*)&Y[(size_t)erow * IC_ + col] = v;
    }
}

// ------------ final: out = relu( Wf . avT + bfv + xA ), fp32 out (batched)
__global__ __launch_bounds__(256) void out_mfma_k(
    const bf16_t* __restrict__ Wfb, const float* __restrict__ bfv,
    const bf16_t* __restrict__ avTb,
    const float* __restrict__ xA, float* __restrict__ out)
{
    __shared__ bf16_t smem[16384];
    const int b = blockIdx.z;
    const bf16_t* Bt = avTb + (size_t)b * N_ * IC_;
    const int n0 = blockIdx.x * 128, o0 = blockIdx.y * 128;

    f32x4 acc[4][4];
    ACC_ZERO(acc);
    gemm_bt_128x128(Wfb, IC_, Bt, IC_, IC_, 0, o0, n0, smem, smem + 8192, acc);

    const int lane = threadIdx.x & 63, wave = threadIdx.x >> 6;
    const int q = lane >> 4, l15 = lane & 15;
    const int wr = (wave >> 1) * 64, wc = (wave & 1) * 64;

#pragma unroll
    for (int i = 0; i < 4; ++i)
#pragma unroll
        for (int r = 0; r < 4; ++r) {
            const int o = o0 + wr + i * 16 + q * 4 + r;
            const float bo = bfv[o];
#pragma unroll
            for (int j = 0; j < 4; ++j) {
                const int n = n0 + wc + j * 16 + l15;
                const size_t idx = ((size_t)b * C_ + o) * N_ + n;
                out[idx] = fmaxf(acc[i][j][r] + bo + xA[idx], 0.f);
            }
        }
}

// ---------------------------------------------------------------- launcher
extern "C" void kernel_launch(void* const* d_in, const int* in_sizes, int n_in,
                              void* d_out, int out_size, void* d_ws, size_t ws_size,
                              hipStream_t stream)
{
    const float* xA    = (const float*)d_in[0];
    const float* wk    = (const float*)d_in[1];
    const float* bk    = (const float*)d_in[2];
    const float* wv    = (const float*)d_in[3];
    const float* bv    = (const float*)d_in[4];
    const float* wq    = (const float*)d_in[5];
    const float* bq    = (const float*)d_in[6];
    const float* wwg   = (const float*)d_in[7];
    const float* bn1_g = (const float*)d_in[8];
    const float* bn1_b = (const float*)d_in[9];
    const float* bn1_m = (const float*)d_in[10];
    const float* bn1_v = (const float*)d_in[11];
    const float* wout  = (const float*)d_in[12];
    const float* bout  = (const float*)d_in[13];
    const float* bn2_g = (const float*)d_in[14];
    const float* bn2_b = (const float*)d_in[15];
    const float* bn2_m = (const float*)d_in[16];
    const float* bn2_v = (const float*)d_in[17];
    float* out = (float*)d_out;

    // ---- workspace layout (178 MB of 256 MiB) ----
    char* p = (char*)d_ws;
    bf16_t* Wb3    = (bf16_t*)p; p += 786432;      // wk|wv|wq bf16
    bf16_t* Wfb    = (bf16_t*)p; p += 262144;      // composed weight [512,256]
    float*  bfv    = (float*)p;  p += 2048;        // composed bias [512]
    bf16_t* xAt    = (bf16_t*)p;                   // [b,n,c] bf16 (dead after conv)
    bf16_t* avTb   = (bf16_t*)p; p += 16777216;    // ALIAS: [b,m,c] bf16 (8.4MB used)
    bf16_t* Kb     = (bf16_t*)p; p += 8388608;     // [b,c,n] (scaled in-place)
    bf16_t* Vt     = (bf16_t*)p; p += 8388608;     // [b,n,c]
    bf16_t* Qt     = (bf16_t*)p; p += 8388608;     // [b,n,c]
    float*  rowsum = (float*)p;  p += 65536;       // [b,n]
    bf16_t* Pt     = (bf16_t*)p; p += 134217728;   // [b,m,n] bf16, all batches

    prep_k<<<2112, 256, 0, stream>>>(wk, wv, wq, wwg, wout, bout,
                                     bn1_g, bn1_b, bn1_m, bn1_v,
                                     bn2_g, bn2_b, bn2_m, bn2_v,
                                     Wb3, Wfb, bfv, rowsum);
    txa_k<<<dim3(N_ / 32, C_ / 32, B_), dim3(32, 8), 0, stream>>>(xA, xAt);
    conv_mfma_k<<<dim3(N_ / 128, IC_ / 128, 3 * B_), 256, 0, stream>>>(
        Wb3, bk, bv, bq, xAt, Kb, Vt, Qt);

    s_mfma_t_k<<<dim3(N_ / 128, N_ / 128, B_), 256, 0, stream>>>(
        Qt, Vt, Pt, rowsum);
    kscale_k<<<2048, 256, 0, stream>>>(Kb, rowsum);
    av_mfma_k<<<dim3(N_ / 64, B_), 256, 0, stream>>>(Pt, Kb, avTb);

    out_mfma_k<<<dim3(N_ / 128, C_ / 128, B_), 256, 0, stream>>>(
        Wfb, bfv, avTb, xA, out);
}

// Round 8
// 309.002 us; speedup vs baseline: 1.0708x; 1.0708x over previous
//
#include <hip/hip_runtime.h>

// MFB fused non-local block, round 8.
// r7's av (64m x 256c, grid 256 = 1 block/CU) was latency-exposed: no
// co-resident block to overlap the 36KB/iter staging. Round 8: av tile
// 32m x 256c -> 512 blocks (2/CU), keeping Pt-read-once + direct bf16 out.

#define N_ 4096
#define C_ 512
#define IC_ 256
#define B_ 4

typedef __bf16 bf16_t;
typedef __bf16 bf16x8 __attribute__((ext_vector_type(8)));
typedef __bf16 bf16x4 __attribute__((ext_vector_type(4)));
typedef float f32x4 __attribute__((ext_vector_type(4)));

#define GLD(g, l) __builtin_amdgcn_global_load_lds(                              \
    (const __attribute__((address_space(1))) void*)(g),                          \
    (__attribute__((address_space(3))) void*)(l), 16, 0, 0)

// ---------------------------------------------------------------------------
// C[128x128] += A[m0.., K] * Bt[n0.., K]^T, bf16 in, fp32 acc. K mult of 64.
// 256 threads = 4 waves; wave (wr,wc) owns 64x64; acc[4][4] of f32x4.
// C/D layout (m89/m91): (i,j,reg) -> row wr+i*16+q*4+reg, col wc+j*16+l15.
// LDS: XOR-swizzled 64-elem rows; slot (row, c) holds global chunk c^(row&7).
// ---------------------------------------------------------------------------
__device__ __forceinline__ void gemm_bt_128x128(
    const bf16_t* __restrict__ A, int lda,
    const bf16_t* __restrict__ Bt, int ldb,
    int K, int kt0, int m0, int n0,
    bf16_t* lsA, bf16_t* lsB, f32x4 acc[4][4])
{
    const int tid  = threadIdx.x;
    const int wave = tid >> 6, lane = tid & 63;
    const int wr = (wave >> 1) * 64, wc = (wave & 1) * 64;
    const int q = lane >> 4, l15 = lane & 15;
    const int srow = lane >> 3;                         // 0..7
    const int scol = (((lane & 7) ^ (srow & 7)) * 8);   // swizzled 8-elem chunk
    const int swz  = l15 & 7;

    for (int kt = kt0; kt < kt0 + K; kt += 64) {
#pragma unroll
        for (int c = 0; c < 4; ++c) {
            const int ch = wave * 4 + c;
            GLD(A  + (size_t)(m0 + ch * 8 + srow) * lda + kt + scol, lsA + ch * 512);
            GLD(Bt + (size_t)(n0 + ch * 8 + srow) * ldb + kt + scol, lsB + ch * 512);
        }
        __syncthreads();
#pragma unroll
        for (int ks = 0; ks < 2; ++ks) {
            bf16x8 af[4], bfr[4];
            const int co = ((ks * 4 + q) ^ swz) * 8;
#pragma unroll
            for (int i = 0; i < 4; ++i) {
                af[i]  = *(const bf16x8*)&lsA[(wr + i * 16 + l15) * 64 + co];
                bfr[i] = *(const bf16x8*)&lsB[(wc + i * 16 + l15) * 64 + co];
            }
#pragma unroll
            for (int i = 0; i < 4; ++i)
#pragma unroll
                for (int j = 0; j < 4; ++j)
                    acc[i][j] = __builtin_amdgcn_mfma_f32_16x16x32_bf16(
                        af[i], bfr[j], acc[i][j], 0, 0, 0);
        }
        __syncthreads();
    }
}

#define ACC_ZERO(acc)                                                           \
    _Pragma("unroll") for (int i = 0; i < 4; ++i)                               \
    _Pragma("unroll") for (int j = 0; j < 4; ++j)                               \
        acc[i][j] = f32x4{0.f, 0.f, 0.f, 0.f};

// ---- prep: castw3 (blocks 0..1535) | wf compose (1536..2047) | zero rowsum
__global__ __launch_bounds__(256) void prep_k(
    const float* __restrict__ wk, const float* __restrict__ wv,
    const float* __restrict__ wq,
    const float* __restrict__ wwg, const float* __restrict__ wout,
    const float* __restrict__ bout,
    const float* __restrict__ g1, const float* __restrict__ b1,
    const float* __restrict__ m1, const float* __restrict__ v1,
    const float* __restrict__ g2, const float* __restrict__ b2,
    const float* __restrict__ m2, const float* __restrict__ v2,
    bf16_t* __restrict__ Wb3, bf16_t* __restrict__ Wfb,
    float* __restrict__ bfv, float* __restrict__ rowsum)
{
    const int bid = blockIdx.x;
    __shared__ float ws[256];
    __shared__ float red[4];

    if (bid < 1536) {                 // cast wk|wv|wq to bf16
        const int i = bid * 256 + threadIdx.x;
        float v;
        if      (i < 131072) v = wk[i];
        else if (i < 262144) v = wv[i - 131072];
        else                 v = wq[i - 262144];
        Wb3[i] = (bf16_t)v;
    } else if (bid < 2048) {          // Wf = diag(s2) wout diag(s1) wwg + bias
        const int o = bid - 1536;     // 0..511
        const int j = threadIdx.x;    // 0..255
        const float s1 = g1[j] * rsqrtf(v1[j] + 1e-5f);
        const float wo = wout[o * 256 + j];
        ws[j] = wo * s1;
        float bp = wo * (b1[j] - m1[j] * s1);
#pragma unroll
        for (int off = 32; off > 0; off >>= 1) bp += __shfl_down(bp, off);
        if ((j & 63) == 0) red[j >> 6] = bp;
        __syncthreads();

        float acc = 0.f;
#pragma unroll 4
        for (int ic = 0; ic < 256; ++ic)
            acc += ws[ic] * wwg[ic * 256 + j];

        const float s2 = g2[o] * rsqrtf(v2[o] + 1e-5f);
        Wfb[o * 256 + j] = (bf16_t)(acc * s2);
        if (j == 0)
            bfv[o] = s2 * (red[0] + red[1] + red[2] + red[3] + bout[o])
                     - s2 * m2[o] + b2[o];
    } else {                          // zero rowsum[b][n] (16384 floats)
        rowsum[(bid - 2048) * 256 + threadIdx.x] = 0.f;
    }
}

// --------------------------------------------- xA [b,c,n] -> xAt [b,n,c] bf16
__global__ __launch_bounds__(256) void txa_k(
    const float* __restrict__ xA, bf16_t* __restrict__ xAt)
{
    __shared__ float t[32][33];
    const int b = blockIdx.z;
    const int n0 = blockIdx.x * 32, c0 = blockIdx.y * 32;
    const int tx = threadIdx.x, ty = threadIdx.y;
    const float* X = xA + (size_t)b * C_ * N_;
    bf16_t* Y = xAt + (size_t)b * N_ * C_;
#pragma unroll
    for (int r = 0; r < 4; ++r)
        t[ty + r * 8][tx] = X[(size_t)(c0 + ty + r * 8) * N_ + n0 + tx];
    __syncthreads();
#pragma unroll
    for (int r = 0; r < 4; ++r)
        Y[(size_t)(n0 + ty + r * 8) * C_ + c0 + tx] = (bf16_t)t[tx][ty + r * 8];
}

// ------------------------------------------ conv KVQ: W[o,c] * xAt[n,c]^T
__global__ __launch_bounds__(256) void conv_mfma_k(
    const bf16_t* __restrict__ Wb3,
    const float* __restrict__ bk, const float* __restrict__ bv,
    const float* __restrict__ bq, const bf16_t* __restrict__ xAt,
    bf16_t* __restrict__ Kb, bf16_t* __restrict__ Vt, bf16_t* __restrict__ Qt)
{
    __shared__ bf16_t smem[16384];
    const int which = blockIdx.z % 3, b = blockIdx.z / 3;
    const bf16_t* A = Wb3 + which * 131072;
    const float* bias = (which == 0) ? bk : (which == 1 ? bv : bq);
    const bf16_t* Bt = xAt + (size_t)b * N_ * C_;
    const int n0 = blockIdx.x * 128, m0 = blockIdx.y * 128;

    f32x4 acc[4][4];
    ACC_ZERO(acc);
    gemm_bt_128x128(A, C_, Bt, C_, C_, 0, m0, n0, smem, smem + 8192, acc);

    const int lane = threadIdx.x & 63, wave = threadIdx.x >> 6;
    const int q = lane >> 4, l15 = lane & 15;
    const int wr = (wave >> 1) * 64, wc = (wave & 1) * 64;

    if (which == 0) {                     // K: [c, n], n contiguous
        bf16_t* Y = Kb + (size_t)b * IC_ * N_;
#pragma unroll
        for (int i = 0; i < 4; ++i)
#pragma unroll
            for (int r = 0; r < 4; ++r) {
                const int o = m0 + wr + i * 16 + q * 4 + r;
                const float bo = bias[o];
#pragma unroll
                for (int j = 0; j < 4; ++j)
                    Y[(size_t)o * N_ + n0 + wc + j * 16 + l15] =
                        (bf16_t)(acc[i][j][r] + bo);
            }
    } else {                              // V/Q: [n, c], c contiguous
        bf16_t* Y = ((which == 1) ? Vt : Qt) + (size_t)b * N_ * IC_;
#pragma unroll
        for (int i = 0; i < 4; ++i) {
            const int ob = m0 + wr + i * 16 + q * 4;
            float bo[4];
#pragma unroll
            for (int r = 0; r < 4; ++r) bo[r] = bias[ob + r];
#pragma unroll
            for (int j = 0; j < 4; ++j) {
                const int n = n0 + wc + j * 16 + l15;
                bf16x4 v4;
#pragma unroll
                for (int r = 0; r < 4; ++r) v4[r] = (bf16_t)(acc[i][j][r] + bo[r]);
                *(bf16x4*)&Y[(size_t)n * IC_ + ob] = v4;
            }
        }
    }
}

// ---- S^T GEMM (batched): D[m,n]=Qt[m,:].Vt[n,:]; write Pt[b][m,n]=exp bf16,
//      rowsum[b][n] += column sums. LDS stage (stride 136) -> b128 stores.
__global__ __launch_bounds__(256) void s_mfma_t_k(
    const bf16_t* __restrict__ Qt, const bf16_t* __restrict__ Vt,
    bf16_t* __restrict__ Pt, float* __restrict__ rowsum)
{
    __shared__ bf16_t smem[17408];
    const int b  = blockIdx.z;
    const int n0 = blockIdx.x * 128;      // cols (n)
    const int m0 = blockIdx.y * 128;      // rows (m)
    const size_t NIC = (size_t)N_ * IC_;
    const bf16_t* Qb = Qt + (size_t)b * NIC;
    const bf16_t* Vb = Vt + (size_t)b * NIC;
    bf16_t* Pb = Pt + (size_t)b * N_ * N_;
    float* rs = rowsum + b * N_;

    f32x4 acc[4][4];
    ACC_ZERO(acc);
    gemm_bt_128x128(Qb, IC_, Vb, IC_, IC_, 0, m0, n0, smem, smem + 8192, acc);

    const int tid = threadIdx.x;
    const int lane = tid & 63, wave = tid >> 6;
    const int q = lane >> 4, l15 = lane & 15;
    const int wr = (wave >> 1) * 64, wc = (wave & 1) * 64;

#pragma unroll
    for (int j = 0; j < 4; ++j) {
        float cs = 0.f;
#pragma unroll
        for (int i = 0; i < 4; ++i)
#pragma unroll
            for (int r = 0; r < 4; ++r) {
                const float e = __expf(acc[i][j][r]);
                cs += e;
                smem[(wr + i * 16 + q * 4 + r) * 136 + wc + j * 16 + l15] = (bf16_t)e;
            }
        cs += __shfl_xor(cs, 16);
        cs += __shfl_xor(cs, 32);
        if (q == 0) atomicAdd(&rs[n0 + wc + j * 16 + l15], cs);
    }
    __syncthreads();

    const int rr = tid >> 4;              // 0..15
    const int cc = (tid & 15) * 8;        // 0..120
#pragma unroll
    for (int p = 0; p < 8; ++p) {
        const int mm = rr + p * 16;
        const bf16x8 v = *(const bf16x8*)&smem[mm * 136 + cc];
        *(bf16x8*)&Pb[(size_t)(m0 + mm) * N_ + n0 + cc] = v;
    }
}

// --------------- K'[b][c,n] = K[b][c,n] / rowsum[b][n], in-place (batched)
__global__ __launch_bounds__(256) void kscale_k(
    bf16_t* __restrict__ Kb, const float* __restrict__ rowsum)
{
    const size_t i8 = ((size_t)blockIdx.x * 256 + threadIdx.x) * 8;  // 2048 blocks
    const int n = (int)(i8 & (N_ - 1));
    const int b = (int)(i8 >> 20);                 // IC_*N_ = 2^20
    const float* rs = rowsum + b * N_;
    bf16x8 v = *(bf16x8*)&Kb[i8];
    const f32x4 r0 = *(const f32x4*)&rs[n];
    const f32x4 r1 = *(const f32x4*)&rs[n + 4];
#pragma unroll
    for (int k = 0; k < 4; ++k) {
        v[k]     = (bf16_t)((float)v[k]     / r0[k]);
        v[4 + k] = (bf16_t)((float)v[4 + k] / r1[k]);
    }
    *(bf16x8*)&Kb[i8] = v;
}

// ---- av GEMM: wg = 32m x 256c, splitK=1, grid 128x4 = 512 blocks (2/CU).
//      avTb[b][m][c] = Pt[b][m,:].K'[b][c,:]^T; Pt read once; direct bf16 out.
__global__ __launch_bounds__(256) void av_mfma_k(
    const bf16_t* __restrict__ Pt, const bf16_t* __restrict__ Kb,
    bf16_t* __restrict__ avTb)
{
    __shared__ bf16_t smem[18432];        // lsA 32x64 (4KB) | lsB 256x64 (32KB)
    bf16_t* lsA = smem;
    bf16_t* lsB = smem + 2048;
    const int b  = blockIdx.y;
    const int m0 = blockIdx.x * 32;
    const size_t NIC = (size_t)N_ * IC_;
    const bf16_t* Pb  = Pt + (size_t)b * N_ * N_ + (size_t)m0 * N_;
    const bf16_t* Kbb = Kb + (size_t)b * NIC;

    const int tid = threadIdx.x;
    const int wave = tid >> 6, lane = tid & 63;
    const int q = lane >> 4, l15 = lane & 15;
    const int srow = lane >> 3;
    const int scol = (((lane & 7) ^ (srow & 7)) * 8);
    const int swz  = l15 & 7;

    f32x4 acc[2][4];
#pragma unroll
    for (int i = 0; i < 2; ++i)
#pragma unroll
        for (int j = 0; j < 4; ++j) acc[i][j] = f32x4{0.f, 0.f, 0.f, 0.f};

    for (int kt = 0; kt < N_; kt += 64) {
        // A: 4 chunks of 8 m-rows; wave w stages chunk w
        GLD(Pb + (size_t)(wave * 8 + srow) * N_ + kt + scol, lsA + wave * 512);
#pragma unroll
        for (int c = 0; c < 8; ++c) {     // B: 32 chunks of 8 c-rows
            const int ch = wave * 8 + c;
            GLD(Kbb + (size_t)(ch * 8 + srow) * N_ + kt + scol, lsB + ch * 512);
        }
        __syncthreads();
#pragma unroll
        for (int ks = 0; ks < 2; ++ks) {
            const int co = ((ks * 4 + q) ^ swz) * 8;
            bf16x8 af[2], bfr[4];
#pragma unroll
            for (int i = 0; i < 2; ++i)
                af[i]  = *(const bf16x8*)&lsA[(i * 16 + l15) * 64 + co];
#pragma unroll
            for (int j = 0; j < 4; ++j)
                bfr[j] = *(const bf16x8*)&lsB[(wave * 64 + j * 16 + l15) * 64 + co];
#pragma unroll
            for (int i = 0; i < 2; ++i)
#pragma unroll
                for (int j = 0; j < 4; ++j)
                    acc[i][j] = __builtin_amdgcn_mfma_f32_16x16x32_bf16(
                        af[i], bfr[j], acc[i][j], 0, 0, 0);
        }
        __syncthreads();
    }

    // epilogue: stage 32 x 256 bf16 (stride 264, 16B-aligned rows) -> b128 rows
#pragma unroll
    for (int i = 0; i < 2; ++i)
#pragma unroll
        for (int j = 0; j < 4; ++j)
#pragma unroll
            for (int r = 0; r < 4; ++r)
                smem[(i * 16 + q * 4 + r) * 264 + wave * 64 + j * 16 + l15] =
                    (bf16_t)acc[i][j][r];
    __syncthreads();

    bf16_t* Y = avTb + (size_t)b * NIC + (size_t)m0 * IC_;
    const int erow = tid >> 3;            // 0..31
    const int ecol = (tid & 7) * 8;       // 0..56
#pragma unroll
    for (int p = 0; p < 4; ++p) {
        const int col = ecol + p * 64;
        const bf16x8 v = *(const bf16x8*)&smem[erow * 264 + col];
        *(bf16x8*)&Y[(size_t)erow * IC_ + col] = v;
    }
}

// ------------ final: out = relu( Wf . avT + bfv + xA ), fp32 out (batched)
__global__ __launch_bounds__(256) void out_mfma_k(
    const bf16_t* __restrict__ Wfb, const float* __restrict__ bfv,
    const bf16_t* __restrict__ avTb,
    const float* __restrict__ xA, float* __restrict__ out)
{
    __shared__ bf16_t smem[16384];
    const int b = blockIdx.z;
    const bf16_t* Bt = avTb + (size_t)b * N_ * IC_;
    const int n0 = blockIdx.x * 128, o0 = blockIdx.y * 128;

    f32x4 acc[4][4];
    ACC_ZERO(acc);
    gemm_bt_128x128(Wfb, IC_, Bt, IC_, IC_, 0, o0, n0, smem, smem + 8192, acc);

    const int lane = threadIdx.x & 63, wave = threadIdx.x >> 6;
    const int q = lane >> 4, l15 = lane & 15;
    const int wr = (wave >> 1) * 64, wc = (wave & 1) * 64;

#pragma unroll
    for (int i = 0; i < 4; ++i)
#pragma unroll
        for (int r = 0; r < 4; ++r) {
            const int o = o0 + wr + i * 16 + q * 4 + r;
            const float bo = bfv[o];
#pragma unroll
            for (int j = 0; j < 4; ++j) {
                const int n = n0 + wc + j * 16 + l15;
                const size_t idx = ((size_t)b * C_ + o) * N_ + n;
                out[idx] = fmaxf(acc[i][j][r] + bo + xA[idx], 0.f);
            }
        }
}

// ---------------------------------------------------------------- launcher
extern "C" void kernel_launch(void* const* d_in, const int* in_sizes, int n_in,
                              void* d_out, int out_size, void* d_ws, size_t ws_size,
                              hipStream_t stream)
{
    const float* xA    = (const float*)d_in[0];
    const float* wk    = (const float*)d_in[1];
    const float* bk    = (const float*)d_in[2];
    const float* wv    = (const float*)d_in[3];
    const float* bv    = (const float*)d_in[4];
    const float* wq    = (const float*)d_in[5];
    const float* bq    = (const float*)d_in[6];
    const float* wwg   = (const float*)d_in[7];
    const float* bn1_g = (const float*)d_in[8];
    const float* bn1_b = (const float*)d_in[9];
    const float* bn1_m = (const float*)d_in[10];
    const float* bn1_v = (const float*)d_in[11];
    const float* wout  = (const float*)d_in[12];
    const float* bout  = (const float*)d_in[13];
    const float* bn2_g = (const float*)d_in[14];
    const float* bn2_b = (const float*)d_in[15];
    const float* bn2_m = (const float*)d_in[16];
    const float* bn2_v = (const float*)d_in[17];
    float* out = (float*)d_out;

    // ---- workspace layout (178 MB of 256 MiB) ----
    char* p = (char*)d_ws;
    bf16_t* Wb3    = (bf16_t*)p; p += 786432;      // wk|wv|wq bf16
    bf16_t* Wfb    = (bf16_t*)p; p += 262144;      // composed weight [512,256]
    float*  bfv    = (float*)p;  p += 2048;        // composed bias [512]
    bf16_t* xAt    = (bf16_t*)p;                   // [b,n,c] bf16 (dead after conv)
    bf16_t* avTb   = (bf16_t*)p; p += 16777216;    // ALIAS: [b,m,c] bf16 (8.4MB used)
    bf16_t* Kb     = (bf16_t*)p; p += 8388608;     // [b,c,n] (scaled in-place)
    bf16_t* Vt     = (bf16_t*)p; p += 8388608;     // [b,n,c]
    bf16_t* Qt     = (bf16_t*)p; p += 8388608;     // [b,n,c]
    float*  rowsum = (float*)p;  p += 65536;       // [b,n]
    bf16_t* Pt     = (bf16_t*)p; p += 134217728;   // [b,m,n] bf16, all batches

    prep_k<<<2112, 256, 0, stream>>>(wk, wv, wq, wwg, wout, bout,
                                     bn1_g, bn1_b, bn1_m, bn1_v,
                                     bn2_g, bn2_b, bn2_m, bn2_v,
                                     Wb3, Wfb, bfv, rowsum);
    txa_k<<<dim3(N_ / 32, C_ / 32, B_), dim3(32, 8), 0, stream>>>(xA, xAt);
    conv_mfma_k<<<dim3(N_ / 128, IC_ / 128, 3 * B_), 256, 0, stream>>>(
        Wb3, bk, bv, bq, xAt, Kb, Vt, Qt);

    s_mfma_t_k<<<dim3(N_ / 128, N_ / 128, B_), 256, 0, stream>>>(
        Qt, Vt, Pt, rowsum);
    kscale_k<<<2048, 256, 0, stream>>>(Kb, rowsum);
    av_mfma_k<<<dim3(N_ / 32, B_), 256, 0, stream>>>(Pt, Kb, avTb);

    out_mfma_k<<<dim3(N_ / 128, C_ / 128, B_), 256, 0, stream>>>(
        Wfb, bfv, avTb, xA, out);
}